// Round 1
// baseline (1771.160 us; speedup 1.0000x reference)
//
#include <hip/hip_runtime.h>
#include <cstddef>

constexpr int B = 16, S = 512, E = 128, I = 256, DHm = 64;
constexpr int BS = B * S;

// ---------------- LayerNorm over E=128, one wave per row ----------------
__global__ void ln_kernel(const float* __restrict__ x, const float* __restrict__ w,
                          float* __restrict__ y) {
  int r = blockIdx.x, l = threadIdx.x;  // 64 threads
  float2 v = *(const float2*)(x + (size_t)r * E + l * 2);
  float s1 = v.x + v.y, s2 = v.x * v.x + v.y * v.y;
#pragma unroll
  for (int m = 32; m; m >>= 1) { s1 += __shfl_xor(s1, m); s2 += __shfl_xor(s2, m); }
  float mu = s1 * (1.f / E);
  float var = s2 * (1.f / E) - mu * mu;
  float rr = rsqrtf(var + 1e-5f);
  float2 wv = *(const float2*)(w + l * 2);
  float2 o;
  o.x = (v.x - mu) * rr * wv.x;
  o.y = (v.y - mu) * rr * wv.y;
  *(float2*)(y + (size_t)r * E + l * 2) = o;
}

// ---------------- Generic f32 GEMM: C[M,N] = A[M,K]@W[K,N] (opt +=) ----------------
template <bool ADD>
__global__ void __launch_bounds__(256) gemm_kernel(const float* __restrict__ A,
                                                   const float* __restrict__ W,
                                                   float* __restrict__ C, int M, int N, int K) {
  __shared__ float As[32][64];  // transposed: As[k][m]
  __shared__ float Ws[32][64];
  const int n0 = blockIdx.x * 64, m0 = blockIdx.y * 64;
  const int tid = threadIdx.x;
  const int tr = tid >> 4, tc = tid & 15;
  float acc[4][4] = {};
  for (int k0 = 0; k0 < K; k0 += 32) {
#pragma unroll
    for (int i = 0; i < 2; i++) {
      int lin = tid + i * 256;
      int mm = lin >> 3, kq = lin & 7;
      float4 a4 = *(const float4*)(A + (size_t)(m0 + mm) * K + (k0 + kq * 4));
      As[kq * 4 + 0][mm] = a4.x; As[kq * 4 + 1][mm] = a4.y;
      As[kq * 4 + 2][mm] = a4.z; As[kq * 4 + 3][mm] = a4.w;
      int kk = lin >> 4, nq = lin & 15;
      float4 w4 = *(const float4*)(W + (size_t)(k0 + kk) * N + (n0 + nq * 4));
      *(float4*)&Ws[kk][nq * 4] = w4;
    }
    __syncthreads();
#pragma unroll
    for (int k = 0; k < 32; k++) {
      float4 a4 = *(const float4*)&As[k][tr * 4];
      float4 b4 = *(const float4*)&Ws[k][tc * 4];
      float av[4] = {a4.x, a4.y, a4.z, a4.w};
      float bv[4] = {b4.x, b4.y, b4.z, b4.w};
#pragma unroll
      for (int ii = 0; ii < 4; ii++)
#pragma unroll
        for (int jj = 0; jj < 4; jj++) acc[ii][jj] += av[ii] * bv[jj];
    }
    __syncthreads();
  }
#pragma unroll
  for (int ii = 0; ii < 4; ii++) {
    float* cp = C + (size_t)(m0 + tr * 4 + ii) * N + n0 + tc * 4;
    float4 o;
    if (ADD) {
      float4 c4 = *(const float4*)cp;
      o = make_float4(c4.x + acc[ii][0], c4.y + acc[ii][1], c4.z + acc[ii][2], c4.w + acc[ii][3]);
    } else {
      o = make_float4(acc[ii][0], acc[ii][1], acc[ii][2], acc[ii][3]);
    }
    *(float4*)cp = o;
  }
}

// ---------------- Causal depthwise conv (K=4) + SiLU ----------------
__global__ void conv_silu_kernel(const float* __restrict__ x, int xstride,
                                 const float* __restrict__ W, const float* __restrict__ bv,
                                 float* __restrict__ y, int C) {
  int r = blockIdx.x, c = threadIdx.x;  // blockDim = C
  int s = r & (S - 1);
  const float* xr = x + (size_t)r * xstride + c;
  float4 w4 = *(const float4*)(W + c * 4);
  float acc = bv[c];
  if (s >= 3) acc += xr[-3 * xstride] * w4.x;
  if (s >= 2) acc += xr[-2 * xstride] * w4.y;
  if (s >= 1) acc += xr[-1 * xstride] * w4.z;
  acc += xr[0] * w4.w;
  y[(size_t)r * C + c] = acc / (1.f + __expf(-acc));
}

// ---------------- headwise q/k/v (64 blocks of 4x4) ----------------
__global__ void qkv_kernel(const float* __restrict__ xc, const float* __restrict__ up,
                           const float* __restrict__ qW, const float* __restrict__ kW,
                           const float* __restrict__ vW, float* __restrict__ Q,
                           float* __restrict__ Kb, float* __restrict__ V) {
  __shared__ float xcl[I], xml[I];
  int r = blockIdx.x, t = threadIdx.x;  // 256 threads
  xcl[t] = xc[(size_t)r * I + t];
  xml[t] = up[(size_t)r * (2 * I) + t];
  __syncthreads();
  int n = t >> 2, o = t & 3;
  const float* qw = qW + n * 16 + o * 4;
  const float* kw = kW + n * 16 + o * 4;
  const float* vw = vW + n * 16 + o * 4;
  float q = 0, k = 0, v = 0;
#pragma unroll
  for (int i = 0; i < 4; i++) {
    float xcv = xcl[n * 4 + i], xmv = xml[n * 4 + i];
    q += xcv * qw[i]; k += xcv * kw[i]; v += xmv * vw[i];
  }
  Q[(size_t)r * I + t] = q;
  Kb[(size_t)r * I + t] = k;
  V[(size_t)r * I + t] = v;
}

// ---------------- ig/fg gate projections (K=768 -> 4 heads) ----------------
__global__ void gates_kernel(const float* __restrict__ Q, const float* __restrict__ Kb,
                             const float* __restrict__ V, const float* __restrict__ igW,
                             const float* __restrict__ igb, const float* __restrict__ fgW,
                             const float* __restrict__ fgb, float* __restrict__ IG,
                             float* __restrict__ FG) {
  int r = blockIdx.x, l = threadIdx.x;  // 64 threads
  float ai[4] = {}, af[4] = {};
#pragma unroll
  for (int j = 0; j < 12; j++) {
    int c = l + j * 64;
    float g = (c < 256) ? Q[(size_t)r * I + c]
              : (c < 512) ? Kb[(size_t)r * I + (c - 256)]
                          : V[(size_t)r * I + (c - 512)];
#pragma unroll
    for (int h = 0; h < 4; h++) {
      ai[h] += g * igW[h * 768 + c];
      af[h] += g * fgW[h * 768 + c];
    }
  }
#pragma unroll
  for (int m = 32; m; m >>= 1)
#pragma unroll
    for (int h = 0; h < 4; h++) {
      ai[h] += __shfl_xor(ai[h], m);
      af[h] += __shfl_xor(af[h], m);
    }
  if (l == 0) {
    int b = r >> 9, s = r & (S - 1);
#pragma unroll
    for (int h = 0; h < 4; h++) {
      IG[((size_t)(b * 4 + h)) * S + s] = ai[h] + igb[h];
      FG[((size_t)(b * 4 + h)) * S + s] = af[h] + fgb[h];
    }
  }
}

// ---------------- decay scan per (b,h): CS=cumsum(logsig(fg)), a=ig-CS, M=prefixmax(a) ----------------
__global__ void decay_kernel(const float* __restrict__ IG, const float* __restrict__ FG,
                             float* __restrict__ Ab, float* __restrict__ Mb,
                             float* __restrict__ Fb) {
  int bh = blockIdx.x, l = threadIdx.x;  // 64 threads, 8 elems each
  const float* ig = IG + (size_t)bh * S;
  const float* fg = FG + (size_t)bh * S;
  float lfc[8], av[8], amx[8];
  float cs = 0;
#pragma unroll
  for (int j = 0; j < 8; j++) {
    float f = fg[l * 8 + j];
    cs += fminf(f, 0.f) - log1pf(__expf(-fabsf(f)));  // log_sigmoid
    lfc[j] = cs;
  }
  float tot = cs, inc = tot;
#pragma unroll
  for (int off = 1; off < 64; off <<= 1) {
    float yv = __shfl_up(inc, off);
    if (l >= off) inc += yv;
  }
  float excl = inc - tot;
  float pm = -1e30f;
#pragma unroll
  for (int j = 0; j < 8; j++) {
    float CSj = excl + lfc[j];
    av[j] = ig[l * 8 + j] - CSj;
    pm = fmaxf(pm, av[j]);
    amx[j] = pm;
    lfc[j] = CSj;  // now holds CS
  }
  float incm = pm;
#pragma unroll
  for (int off = 1; off < 64; off <<= 1) {
    float yv = __shfl_up(incm, off);
    if (l >= off) incm = fmaxf(incm, yv);
  }
  float exclm = __shfl_up(incm, 1);
  if (l == 0) exclm = -1e30f;
#pragma unroll
  for (int j = 0; j < 8; j++) {
    float Mj = fmaxf(exclm, amx[j]);
    Ab[(size_t)bh * S + l * 8 + j] = av[j];
    Mb[(size_t)bh * S + l * 8 + j] = Mj;
    Fb[(size_t)bh * S + l * 8 + j] = __expf(-(lfc[j] + Mj));
  }
}

// ---------------- mLSTM attention: h[s,:] = sum_t qk*exp(a[t]-M[s])*v / norm ----------------
__global__ void __launch_bounds__(256) attn_kernel(const float* __restrict__ Q,
                                                   const float* __restrict__ Kb,
                                                   const float* __restrict__ V,
                                                   const float* __restrict__ Ab,
                                                   const float* __restrict__ Mb,
                                                   const float* __restrict__ Fb,
                                                   float* __restrict__ H) {
  __shared__ float Qt[64][68];  // d-major
  __shared__ float Kt[64][68];  // d-major
  __shared__ float Wl[64][65];  // [s][t]
  __shared__ float Atl[64], Msl[64], Csl[64];
  int bid = blockIdx.x;
  int st = bid & 7, bh = bid >> 3;
  int b = bh >> 2, h = bh & 3;
  int s0 = st * 64;
  int tid = threadIdx.x;
  const float* Qg = Q + ((size_t)b * S) * I + h * DHm;
  const float* Kg = Kb + ((size_t)b * S) * I + h * DHm;
  const float* Vg = V + ((size_t)b * S) * I + h * DHm;
  for (int lin = tid; lin < 4096; lin += 256) {
    int sr = lin >> 6, d = lin & 63;
    Qt[d][sr] = Qg[(size_t)(s0 + sr) * I + d];
  }
  if (tid < 64) Msl[tid] = Mb[(size_t)bh * S + s0 + tid];
  const int sq = tid >> 4, tq = tid & 15;
  float hacc[4][4] = {};
  float cs4[4] = {};
  for (int tt = 0; tt <= st; tt++) {
    int t0 = tt * 64;
    __syncthreads();  // prev phase B done (and Q staging on first iter)
    for (int lin = tid; lin < 4096; lin += 256) {
      int tr = lin >> 6, d = lin & 63;
      Kt[d][tr] = Kg[(size_t)(t0 + tr) * I + d];
    }
    if (tid < 64) Atl[tid] = Ab[(size_t)bh * S + t0 + tid];
    __syncthreads();
    // phase A: w[s,t] = (q.k)*scale*exp(a[t]-M[s]), causal-masked
    float acc[4][4] = {};
#pragma unroll 8
    for (int d = 0; d < 64; d++) {
      float4 q4 = *(const float4*)&Qt[d][sq * 4];
      float4 k4 = *(const float4*)&Kt[d][tq * 4];
      float qa[4] = {q4.x, q4.y, q4.z, q4.w};
      float ka[4] = {k4.x, k4.y, k4.z, k4.w};
#pragma unroll
      for (int ii = 0; ii < 4; ii++)
#pragma unroll
        for (int jj = 0; jj < 4; jj++) acc[ii][jj] += qa[ii] * ka[jj];
    }
#pragma unroll
    for (int ii = 0; ii < 4; ii++)
#pragma unroll
      for (int jj = 0; jj < 4; jj++) {
        int sl = sq * 4 + ii, tl = tq * 4 + jj;
        float w = 0.f;
        if (t0 + tl <= s0 + sl) w = acc[ii][jj] * 0.125f * __expf(Atl[tl] - Msl[sl]);
        Wl[sl][tl] = w;
      }
    __syncthreads();
    // phase B: hacc += w @ v   (v straight from global; L2-resident)
    for (int t = 0; t < 64; t++) {
      float4 v4 = *(const float4*)(Vg + (size_t)(t0 + t) * I + tq * 4);
      float va[4] = {v4.x, v4.y, v4.z, v4.w};
#pragma unroll
      for (int ii = 0; ii < 4; ii++) {
        float w = Wl[sq * 4 + ii][t];
        if (tq == 0) cs4[ii] += w;
#pragma unroll
        for (int jj = 0; jj < 4; jj++) hacc[ii][jj] += w * va[jj];
      }
    }
  }
  if (tq == 0) {
#pragma unroll
    for (int ii = 0; ii < 4; ii++) Csl[sq * 4 + ii] = cs4[ii];
  }
  __syncthreads();
  const float* Fg = Fb + (size_t)bh * S + s0;
#pragma unroll
  for (int ii = 0; ii < 4; ii++) {
    int sl = sq * 4 + ii;
    float norm = fmaxf(fabsf(Csl[sl]), Fg[sl]) + 1e-6f;
    float inv = 1.f / norm;
    float4 o = make_float4(hacc[ii][0] * inv, hacc[ii][1] * inv, hacc[ii][2] * inv,
                           hacc[ii][3] * inv);
    *(float4*)&H[((size_t)(b * S + s0 + sl)) * I + h * DHm + tq * 4] = o;
  }
}

// ---------------- per-head norm (DH=64) + skip + silu(z) gate ----------------
__global__ void outfuse_kernel(const float* __restrict__ H, const float* __restrict__ XC,
                               const float* __restrict__ UP, const float* __restrict__ onw,
                               const float* __restrict__ skip, float* __restrict__ HF) {
  int r = blockIdx.x, t = threadIdx.x;  // 256 threads; wave == head
  float v = H[(size_t)r * I + t];
  float s1 = v, s2 = v * v;
#pragma unroll
  for (int m = 32; m; m >>= 1) { s1 += __shfl_xor(s1, m); s2 += __shfl_xor(s2, m); }
  float mu = s1 * (1.f / 64), var = s2 * (1.f / 64) - mu * mu;
  float hn = (v - mu) * rsqrtf(var + 1e-5f) * onw[t];
  float zv = UP[(size_t)r * (2 * I) + I + t];
  float hf = (hn + skip[t] * XC[(size_t)r * I + t]) * (zv / (1.f + __expf(-zv)));
  HF[(size_t)r * I + t] = hf;
}

// ---------------- sLSTM gate pre-activations ----------------
__global__ void __launch_bounds__(512) slstm_gates_kernel(const float* __restrict__ xn,
                                                          const float* __restrict__ xc,
                                                          const float* __restrict__ gW,
                                                          const float* __restrict__ bias,
                                                          float* __restrict__ GX) {
  __shared__ float xnl[E], xcl[E];
  int r = blockIdx.x, t = threadIdx.x;  // 512 threads: (n,g,o)
  if (t < E) { xnl[t] = xn[(size_t)r * E + t]; xcl[t] = xc[(size_t)r * E + t]; }
  __syncthreads();
  int n = t >> 7, g = (t >> 5) & 3, o = t & 31;
  const float* src = (g < 2) ? (xcl + n * 32) : (xnl + n * 32);
  const float* wp = gW + (((size_t)g * 4 + n) * 32 + o) * 32;
  float acc = bias[n * 128 + g * 32 + o];
#pragma unroll
  for (int d = 0; d < 32; d++) acc += src[d] * wp[d];
  GX[(size_t)r * 512 + t] = acc;
}

// ---------------- sLSTM sequential scan, one block per batch ----------------
__global__ void __launch_bounds__(512) slstm_scan_kernel(const float* __restrict__ GX,
                                                         const float* __restrict__ R,
                                                         float* __restrict__ HS) {
  int b = blockIdx.x, t = threadIdx.x;  // 512: (n, g*32+o)
  int n = t >> 7, gd = t & 127;
  float Rreg[32];
#pragma unroll
  for (int d = 0; d < 32; d++) Rreg[d] = R[((size_t)(n * 32 + d)) * 128 + gd];
  __shared__ float h_l[128];
  __shared__ float raw_l[512];
  if (t < 128) h_l[t] = 0.f;
  float c = 0.f, nn = 0.f, m = 0.f;
  int d = gd & 31;
  bool isstate = (gd < 32);  // g==0 threads own state (n,d)
  const float* gxp = GX + (size_t)b * S * 512 + t;
  float gx_cur = gxp[0];
  __syncthreads();
  for (int s = 0; s < S; s++) {
    float gx_next = (s < S - 1) ? gxp[(size_t)(s + 1) * 512] : 0.f;
    float acc = gx_cur;
    const float4* h4 = (const float4*)(h_l + n * 32);
#pragma unroll
    for (int q = 0; q < 8; q++) {
      float4 hv = h4[q];
      acc += hv.x * Rreg[q * 4] + hv.y * Rreg[q * 4 + 1] + hv.z * Rreg[q * 4 + 2] +
             hv.w * Rreg[q * 4 + 3];
    }
    raw_l[t] = acc;
    __syncthreads();
    if (isstate) {
      float ir = raw_l[n * 128 + d];
      float fr = raw_l[n * 128 + 32 + d];
      float zr = raw_l[n * 128 + 64 + d];
      float og = raw_l[n * 128 + 96 + d];
      float lsf = fminf(fr, 0.f) - log1pf(__expf(-fabsf(fr)));
      float lfm = m + lsf;
      float mn = fmaxf(ir, lfm);
      float iv = __expf(ir - mn), fv = __expf(lfm - mn);
      c = fv * c + iv * tanhf(zr);
      nn = fv * nn + iv;
      m = mn;
      float hv = (1.f / (1.f + __expf(-og))) * c / nn;
      h_l[n * 32 + d] = hv;
      HS[((size_t)(b * S + s)) * E + n * 32 + d] = hv;
    }
    __syncthreads();
    gx_cur = gx_next;
  }
}

// ---------------- sLSTM group-norm (32) + residual add ----------------
__global__ void gnorm_add_kernel(const float* __restrict__ HS, const float* __restrict__ gnw,
                                 float* __restrict__ X) {
  int r = blockIdx.x, t = threadIdx.x;  // 128 threads, groups of 32
  float v = HS[(size_t)r * E + t];
  float s1 = v, s2 = v * v;
#pragma unroll
  for (int m = 16; m; m >>= 1) { s1 += __shfl_xor(s1, m, 32); s2 += __shfl_xor(s2, m, 32); }
  float mu = s1 * (1.f / 32), var = s2 * (1.f / 32) - mu * mu;
  X[(size_t)r * E + t] += (v - mu) * rsqrtf(var + 1e-5f) * gnw[t];
}

// ---------------- GeGLU (exact gelu) ----------------
__global__ void geglu_kernel(const float* __restrict__ U, float* __restrict__ Y) {
  int idx = blockIdx.x * 256 + threadIdx.x;  // BS*192 total
  int r = idx / 192, cc = idx % 192;
  float g = U[(size_t)r * 384 + cc];
  float u = U[(size_t)r * 384 + 192 + cc];
  float ge = 0.5f * g * (1.f + erff(g * 0.70710678118f));
  Y[idx] = ge * u;
}

// ---------------- final LN + FC on last token ----------------
__global__ void head_kernel(const float* __restrict__ X, const float* __restrict__ pw,
                            const float* __restrict__ fcW, const float* __restrict__ fcb,
                            float* __restrict__ out) {
  int b = blockIdx.x, l = threadIdx.x;  // 64
  const float* xr = X + ((size_t)(b * S + S - 1)) * E;
  float2 v = *(const float2*)(xr + l * 2);
  float s1 = v.x + v.y, s2 = v.x * v.x + v.y * v.y;
#pragma unroll
  for (int m = 32; m; m >>= 1) { s1 += __shfl_xor(s1, m); s2 += __shfl_xor(s2, m); }
  float mu = s1 * (1.f / E), var = s2 * (1.f / E) - mu * mu;
  float rr = rsqrtf(var + 1e-5f);
  float2 wv = *(const float2*)(pw + l * 2);
  float2 fw = *(const float2*)(fcW + l * 2);
  float acc = (v.x - mu) * rr * wv.x * fw.x + (v.y - mu) * rr * wv.y * fw.y;
#pragma unroll
  for (int m = 32; m; m >>= 1) acc += __shfl_xor(acc, m);
  if (l == 0) out[b] = acc + fcb[0];
}

extern "C" void kernel_launch(void* const* d_in, const int* in_sizes, int n_in, void* d_out,
                              int out_size, void* d_ws, size_t ws_size, hipStream_t stream) {
  const float* in_x = (const float*)d_in[0];
  const float* m_ln_w = (const float*)d_in[1];
  const float* m_up_W = (const float*)d_in[2];
  const float* m_conv_W = (const float*)d_in[3];
  const float* m_conv_b = (const float*)d_in[4];
  const float* m_q_W = (const float*)d_in[5];
  const float* m_k_W = (const float*)d_in[6];
  const float* m_v_W = (const float*)d_in[7];
  const float* m_ig_W = (const float*)d_in[8];
  const float* m_ig_b = (const float*)d_in[9];
  const float* m_fg_W = (const float*)d_in[10];
  const float* m_fg_b = (const float*)d_in[11];
  const float* m_on_w = (const float*)d_in[12];
  const float* m_skip = (const float*)d_in[13];
  const float* m_down_W = (const float*)d_in[14];
  const float* s_ln_w = (const float*)d_in[15];
  const float* s_conv_W = (const float*)d_in[16];
  const float* s_conv_b = (const float*)d_in[17];
  const float* s_gates_W = (const float*)d_in[18];
  const float* s_R = (const float*)d_in[19];
  const float* s_bias = (const float*)d_in[20];
  const float* s_gn_w = (const float*)d_in[21];
  const float* s_ffn_ln_w = (const float*)d_in[22];
  const float* s_ffn_up_W = (const float*)d_in[23];
  const float* s_ffn_down_W = (const float*)d_in[24];
  const float* post_norm_w = (const float*)d_in[25];
  const float* fc_W = (const float*)d_in[26];
  const float* fc_b = (const float*)d_in[27];

  float* ws = (float*)d_ws;
  float* X = ws;                    // 1,048,576
  float* XN = X + 1048576;          // 1,048,576
  float* UP = XN + 1048576;         // 4,194,304
  float* XC = UP + 4194304;         // 2,097,152
  float* Qb = XC + 2097152;         // 2,097,152
  float* Kb = Qb + 2097152;         // 2,097,152
  float* Vb = Kb + 2097152;         // 2,097,152
  float* Hb = Vb + 2097152;         // 2,097,152
  float* IGb = Hb + 2097152;        // 32,768
  float* FGb = IGb + 32768;
  float* Abuf = FGb + 32768;
  float* Mbuf = Abuf + 32768;
  float* Fbuf = Mbuf + 32768;

  hipMemcpyAsync(X, in_x, (size_t)BS * E * sizeof(float), hipMemcpyDeviceToDevice, stream);

  int mi = 0;
  for (int blk = 0; blk < 7; blk++) {
    if (blk == 1) {
      // ---- sLSTM block ----
      ln_kernel<<<BS, 64, 0, stream>>>(X, s_ln_w, XN);
      conv_silu_kernel<<<BS, E, 0, stream>>>(XN, E, s_conv_W, s_conv_b, XC, E);
      slstm_gates_kernel<<<BS, 512, 0, stream>>>(XN, XC, s_gates_W, s_bias, UP);
      slstm_scan_kernel<<<B, 512, 0, stream>>>(UP, s_R, Hb);
      gnorm_add_kernel<<<BS, E, 0, stream>>>(Hb, s_gn_w, X);
      ln_kernel<<<BS, 64, 0, stream>>>(X, s_ffn_ln_w, XN);
      gemm_kernel<false><<<dim3(384 / 64, BS / 64), 256, 0, stream>>>(XN, s_ffn_up_W, UP, BS, 384, 128);
      geglu_kernel<<<BS * 192 / 256, 256, 0, stream>>>(UP, XC);
      gemm_kernel<true><<<dim3(128 / 64, BS / 64), 256, 0, stream>>>(XC, s_ffn_down_W, X, BS, 128, 192);
    } else {
      // ---- mLSTM block (index mi) ----
      const float* ln_w = m_ln_w + (size_t)mi * E;
      const float* up_W = m_up_W + (size_t)mi * E * 512;
      const float* conv_W = m_conv_W + (size_t)mi * I * 4;
      const float* conv_b = m_conv_b + (size_t)mi * I;
      const float* q_W = m_q_W + (size_t)mi * 1024;
      const float* k_W = m_k_W + (size_t)mi * 1024;
      const float* v_W = m_v_W + (size_t)mi * 1024;
      const float* ig_W = m_ig_W + (size_t)mi * 3072;
      const float* ig_b = m_ig_b + (size_t)mi * 4;
      const float* fg_W = m_fg_W + (size_t)mi * 3072;
      const float* fg_b = m_fg_b + (size_t)mi * 4;
      const float* on_w = m_on_w + (size_t)mi * I;
      const float* skipv = m_skip + (size_t)mi * I;
      const float* down_W = m_down_W + (size_t)mi * I * E;

      ln_kernel<<<BS, 64, 0, stream>>>(X, ln_w, XN);
      gemm_kernel<false><<<dim3(512 / 64, BS / 64), 256, 0, stream>>>(XN, up_W, UP, BS, 512, 128);
      conv_silu_kernel<<<BS, I, 0, stream>>>(UP, 512, conv_W, conv_b, XC, I);
      qkv_kernel<<<BS, I, 0, stream>>>(XC, UP, q_W, k_W, v_W, Qb, Kb, Vb);
      gates_kernel<<<BS, 64, 0, stream>>>(Qb, Kb, Vb, ig_W, ig_b, fg_W, fg_b, IGb, FGb);
      decay_kernel<<<64, 64, 0, stream>>>(IGb, FGb, Abuf, Mbuf, Fbuf);
      attn_kernel<<<512, 256, 0, stream>>>(Qb, Kb, Vb, Abuf, Mbuf, Fbuf, Hb);
      outfuse_kernel<<<BS, I, 0, stream>>>(Hb, XC, UP, on_w, skipv, Qb);  // HF -> Qb
      gemm_kernel<true><<<dim3(128 / 64, BS / 64), 256, 0, stream>>>(Qb, down_W, X, BS, 128, 256);
      mi++;
    }
  }
  head_kernel<<<B, 64, 0, stream>>>(X, post_norm_w, fc_W, fc_b, (float*)d_out);
}

// Round 2
// 1502.164 us; speedup vs baseline: 1.1791x; 1.1791x over previous
//
#include <hip/hip_runtime.h>
#include <cstddef>

constexpr int B = 16, S = 512, E = 128, I = 256, DHm = 64;
constexpr int BS = B * S;

// ---------------- LayerNorm over E=128, one wave per row ----------------
__global__ void ln_kernel(const float* __restrict__ x, const float* __restrict__ w,
                          float* __restrict__ y) {
  int r = blockIdx.x, l = threadIdx.x;  // 64 threads
  float2 v = *(const float2*)(x + (size_t)r * E + l * 2);
  float s1 = v.x + v.y, s2 = v.x * v.x + v.y * v.y;
#pragma unroll
  for (int m = 32; m; m >>= 1) { s1 += __shfl_xor(s1, m); s2 += __shfl_xor(s2, m); }
  float mu = s1 * (1.f / E);
  float var = s2 * (1.f / E) - mu * mu;
  float rr = rsqrtf(var + 1e-5f);
  float2 wv = *(const float2*)(w + l * 2);
  float2 o;
  o.x = (v.x - mu) * rr * wv.x;
  o.y = (v.y - mu) * rr * wv.y;
  *(float2*)(y + (size_t)r * E + l * 2) = o;
}

// ---------------- f32 GEMM: C[M,N] = A[M,K]@W[K,N] (opt +=) ----------------
// BMxBN tile, 256 threads, (BM/16)x(BN/16) outputs per thread.
// A staged transposed (As[k][m]) with k-group XOR swizzle -> 2-way write conflicts.
template <int BM, int BN, bool ADD>
__global__ void __launch_bounds__(256) gemm2(const float* __restrict__ A,
                                             const float* __restrict__ W,
                                             float* __restrict__ C, int M, int N, int K) {
  constexpr int TM = BM / 16, TN = BN / 16;
  __shared__ float As[32][BM];
  __shared__ float Ws[32][BN];
  const int n0 = blockIdx.x * BN, m0 = blockIdx.y * BM;
  const int tid = threadIdx.x;
  const int tr = tid >> 4, tc = tid & 15;
  float acc[TM][TN] = {};
  for (int k0 = 0; k0 < K; k0 += 32) {
#pragma unroll
    for (int i = 0; i < BM / 32; i++) {
      int lin = tid + i * 256;
      int mm = lin >> 3, kq = lin & 7;
      float4 a4 = *(const float4*)(A + (size_t)(m0 + mm) * K + k0 + kq * 4);
      int col = mm ^ (kq * 4);
      As[kq * 4 + 0][col] = a4.x;
      As[kq * 4 + 1][col] = a4.y;
      As[kq * 4 + 2][col] = a4.z;
      As[kq * 4 + 3][col] = a4.w;
    }
#pragma unroll
    for (int i = 0; i < BN / 32; i++) {
      int lin = tid + i * 256;
      int kk = lin / (BN / 4), nq = lin % (BN / 4);
      *(float4*)&Ws[kk][nq * 4] = *(const float4*)(W + (size_t)(k0 + kk) * N + n0 + nq * 4);
    }
    __syncthreads();
#pragma unroll
    for (int k = 0; k < 32; k++) {
      float av[TM], bv[TN];
      const int xs = (k >> 2) * 4;
      *(float4*)&av[0] = *(const float4*)&As[k][(tr * 4) ^ xs];
      if constexpr (TM == 8) *(float4*)&av[4] = *(const float4*)&As[k][((tr * 4) ^ xs) + 64];
      *(float4*)&bv[0] = *(const float4*)&Ws[k][tc * 4];
      if constexpr (TN == 8) *(float4*)&bv[4] = *(const float4*)&Ws[k][tc * 4 + 64];
#pragma unroll
      for (int ii = 0; ii < TM; ii++)
#pragma unroll
        for (int jj = 0; jj < TN; jj++) acc[ii][jj] += av[ii] * bv[jj];
    }
    __syncthreads();
  }
#pragma unroll
  for (int ii = 0; ii < TM; ii++) {
    int row = m0 + tr * 4 + (ii & 3) + ((ii >= 4) ? 64 : 0);
    float* cp = C + (size_t)row * N + n0 + tc * 4;
    float4 o = make_float4(acc[ii][0], acc[ii][1], acc[ii][2], acc[ii][3]);
    if (ADD) {
      float4 c4 = *(const float4*)cp;
      o.x += c4.x; o.y += c4.y; o.z += c4.z; o.w += c4.w;
    }
    *(float4*)cp = o;
    if constexpr (TN == 8) {
      float4 o2 = make_float4(acc[ii][4], acc[ii][5], acc[ii][6], acc[ii][7]);
      if (ADD) {
        float4 c4 = *(const float4*)(cp + 64);
        o2.x += c4.x; o2.y += c4.y; o2.z += c4.z; o2.w += c4.w;
      }
      *(float4*)(cp + 64) = o2;
    }
  }
}

// ---------------- Causal depthwise conv (K=4) + SiLU ----------------
__global__ void conv_silu_kernel(const float* __restrict__ x, int xstride,
                                 const float* __restrict__ W, const float* __restrict__ bv,
                                 float* __restrict__ y, int C) {
  int r = blockIdx.x, c = threadIdx.x;  // blockDim = C
  int s = r & (S - 1);
  const float* xr = x + (size_t)r * xstride + c;
  float4 w4 = *(const float4*)(W + c * 4);
  float acc = bv[c];
  if (s >= 3) acc += xr[-3 * xstride] * w4.x;
  if (s >= 2) acc += xr[-2 * xstride] * w4.y;
  if (s >= 1) acc += xr[-1 * xstride] * w4.z;
  acc += xr[0] * w4.w;
  y[(size_t)r * C + c] = acc / (1.f + __expf(-acc));
}

// ---------------- headwise q/k/v (64 blocks of 4x4) ----------------
__global__ void qkv_kernel(const float* __restrict__ xc, const float* __restrict__ up,
                           const float* __restrict__ qW, const float* __restrict__ kW,
                           const float* __restrict__ vW, float* __restrict__ Q,
                           float* __restrict__ Kb, float* __restrict__ V) {
  __shared__ float xcl[I], xml[I];
  int r = blockIdx.x, t = threadIdx.x;  // 256 threads
  xcl[t] = xc[(size_t)r * I + t];
  xml[t] = up[(size_t)r * (2 * I) + t];
  __syncthreads();
  int n = t >> 2, o = t & 3;
  const float* qw = qW + n * 16 + o * 4;
  const float* kw = kW + n * 16 + o * 4;
  const float* vw = vW + n * 16 + o * 4;
  float q = 0, k = 0, v = 0;
#pragma unroll
  for (int i = 0; i < 4; i++) {
    float xcv = xcl[n * 4 + i], xmv = xml[n * 4 + i];
    q += xcv * qw[i]; k += xcv * kw[i]; v += xmv * vw[i];
  }
  Q[(size_t)r * I + t] = q;
  Kb[(size_t)r * I + t] = k;
  V[(size_t)r * I + t] = v;
}

// ---------------- ig/fg gate projections (K=768 -> 4 heads) ----------------
__global__ void gates_kernel(const float* __restrict__ Q, const float* __restrict__ Kb,
                             const float* __restrict__ V, const float* __restrict__ igW,
                             const float* __restrict__ igb, const float* __restrict__ fgW,
                             const float* __restrict__ fgb, float* __restrict__ IG,
                             float* __restrict__ FG) {
  int r = blockIdx.x, l = threadIdx.x;  // 64 threads
  float ai[4] = {}, af[4] = {};
#pragma unroll
  for (int j = 0; j < 12; j++) {
    int c = l + j * 64;
    float g = (c < 256) ? Q[(size_t)r * I + c]
              : (c < 512) ? Kb[(size_t)r * I + (c - 256)]
                          : V[(size_t)r * I + (c - 512)];
#pragma unroll
    for (int h = 0; h < 4; h++) {
      ai[h] += g * igW[h * 768 + c];
      af[h] += g * fgW[h * 768 + c];
    }
  }
#pragma unroll
  for (int m = 32; m; m >>= 1)
#pragma unroll
    for (int h = 0; h < 4; h++) {
      ai[h] += __shfl_xor(ai[h], m);
      af[h] += __shfl_xor(af[h], m);
    }
  if (l == 0) {
    int b = r >> 9, s = r & (S - 1);
#pragma unroll
    for (int h = 0; h < 4; h++) {
      IG[((size_t)(b * 4 + h)) * S + s] = ai[h] + igb[h];
      FG[((size_t)(b * 4 + h)) * S + s] = af[h] + fgb[h];
    }
  }
}

// ---------------- decay scan per (b,h) ----------------
__global__ void decay_kernel(const float* __restrict__ IG, const float* __restrict__ FG,
                             float* __restrict__ Ab, float* __restrict__ Mb,
                             float* __restrict__ Fb) {
  int bh = blockIdx.x, l = threadIdx.x;  // 64 threads, 8 elems each
  const float* ig = IG + (size_t)bh * S;
  const float* fg = FG + (size_t)bh * S;
  float lfc[8], av[8], amx[8];
  float cs = 0;
#pragma unroll
  for (int j = 0; j < 8; j++) {
    float f = fg[l * 8 + j];
    cs += fminf(f, 0.f) - log1pf(__expf(-fabsf(f)));  // log_sigmoid
    lfc[j] = cs;
  }
  float tot = cs, inc = tot;
#pragma unroll
  for (int off = 1; off < 64; off <<= 1) {
    float yv = __shfl_up(inc, off);
    if (l >= off) inc += yv;
  }
  float excl = inc - tot;
  float pm = -1e30f;
#pragma unroll
  for (int j = 0; j < 8; j++) {
    float CSj = excl + lfc[j];
    av[j] = ig[l * 8 + j] - CSj;
    pm = fmaxf(pm, av[j]);
    amx[j] = pm;
    lfc[j] = CSj;  // now holds CS
  }
  float incm = pm;
#pragma unroll
  for (int off = 1; off < 64; off <<= 1) {
    float yv = __shfl_up(incm, off);
    if (l >= off) incm = fmaxf(incm, yv);
  }
  float exclm = __shfl_up(incm, 1);
  if (l == 0) exclm = -1e30f;
#pragma unroll
  for (int j = 0; j < 8; j++) {
    float Mj = fmaxf(exclm, amx[j]);
    Ab[(size_t)bh * S + l * 8 + j] = av[j];
    Mb[(size_t)bh * S + l * 8 + j] = Mj;
    Fb[(size_t)bh * S + l * 8 + j] = __expf(-(lfc[j] + Mj));
  }
}

// ---------------- mLSTM attention ----------------
__global__ void __launch_bounds__(256) attn_kernel(const float* __restrict__ Q,
                                                   const float* __restrict__ Kb,
                                                   const float* __restrict__ V,
                                                   const float* __restrict__ Ab,
                                                   const float* __restrict__ Mb,
                                                   const float* __restrict__ Fb,
                                                   float* __restrict__ H) {
  __shared__ float Qt[64 * 68];   // [d]*68 + s
  __shared__ float KVt[64 * 68];  // K phase: [d]*68+t ; V phase: [t]*68+d
  __shared__ float Wl[64 * 64];   // [s]*64 + t
  __shared__ float Atl[64], Msl[64], Csl[64];
  int bid = blockIdx.x;
  int st = bid & 7, bh = bid >> 3;
  int b = bh >> 2, h = bh & 3;
  int s0 = st * 64;
  int tid = threadIdx.x;
  const float* Qg = Q + ((size_t)b * S) * I + h * DHm;
  const float* Kg = Kb + ((size_t)b * S) * I + h * DHm;
  const float* Vg = V + ((size_t)b * S) * I + h * DHm;
  for (int lin = tid; lin < 4096; lin += 256) {
    int sr = lin >> 6, d = lin & 63;
    Qt[d * 68 + sr] = Qg[(size_t)(s0 + sr) * I + d];
  }
  if (tid < 64) Msl[tid] = Mb[(size_t)bh * S + s0 + tid];
  const int sq = tid >> 4, tq = tid & 15;
  float hacc[4][4] = {};
  float cs4[4] = {};
  for (int tt = 0; tt <= st; tt++) {
    int t0 = tt * 64;
    __syncthreads();  // prev phase B done (and Q/Msl staged on first iter)
    for (int lin = tid; lin < 4096; lin += 256) {
      int tr = lin >> 6, d = lin & 63;
      KVt[d * 68 + tr] = Kg[(size_t)(t0 + tr) * I + d];
    }
    if (tid < 64) Atl[tid] = Ab[(size_t)bh * S + t0 + tid];
    __syncthreads();
    // phase A: w[s,t] = (q.k)*scale*exp(a[t]-M[s]), causal-masked
    float acc[4][4] = {};
#pragma unroll 8
    for (int d = 0; d < 64; d++) {
      float4 q4 = *(const float4*)&Qt[d * 68 + sq * 4];
      float4 k4 = *(const float4*)&KVt[d * 68 + tq * 4];
      float qa[4] = {q4.x, q4.y, q4.z, q4.w};
      float ka[4] = {k4.x, k4.y, k4.z, k4.w};
#pragma unroll
      for (int ii = 0; ii < 4; ii++)
#pragma unroll
        for (int jj = 0; jj < 4; jj++) acc[ii][jj] += qa[ii] * ka[jj];
    }
#pragma unroll
    for (int ii = 0; ii < 4; ii++) {
      int sl = sq * 4 + ii;
      float4 wv;
      float* wp = &wv.x;
#pragma unroll
      for (int jj = 0; jj < 4; jj++) {
        int tl = tq * 4 + jj;
        wp[jj] = (t0 + tl <= s0 + sl) ? acc[ii][jj] * 0.125f * __expf(Atl[tl] - Msl[sl]) : 0.f;
      }
      *(float4*)&Wl[sl * 64 + tq * 4] = wv;
    }
    __syncthreads();  // Wl ready; K reads done
    for (int lin = tid; lin < 4096; lin += 256) {
      int tr = lin >> 6, d = lin & 63;
      KVt[tr * 68 + d] = Vg[(size_t)(t0 + tr) * I + d];
    }
    __syncthreads();
    // phase B: hacc += w @ v
    for (int t = 0; t < 64; t++) {
      float4 v4 = *(const float4*)&KVt[t * 68 + tq * 4];
      float va[4] = {v4.x, v4.y, v4.z, v4.w};
#pragma unroll
      for (int ii = 0; ii < 4; ii++) {
        float w = Wl[(sq * 4 + ii) * 64 + t];
        if (tq == 0) cs4[ii] += w;
#pragma unroll
        for (int jj = 0; jj < 4; jj++) hacc[ii][jj] += w * va[jj];
      }
    }
  }
  if (tq == 0) {
#pragma unroll
    for (int ii = 0; ii < 4; ii++) Csl[sq * 4 + ii] = cs4[ii];
  }
  __syncthreads();
  const float* Fg = Fb + (size_t)bh * S + s0;
#pragma unroll
  for (int ii = 0; ii < 4; ii++) {
    int sl = sq * 4 + ii;
    float norm = fmaxf(fabsf(Csl[sl]), Fg[sl]) + 1e-6f;
    float inv = 1.f / norm;
    float4 o = make_float4(hacc[ii][0] * inv, hacc[ii][1] * inv, hacc[ii][2] * inv,
                           hacc[ii][3] * inv);
    *(float4*)&H[((size_t)(b * S + s0 + sl)) * I + h * DHm + tq * 4] = o;
  }
}

// ---------------- per-head norm (DH=64) + skip + silu(z) gate ----------------
__global__ void outfuse_kernel(const float* __restrict__ H, const float* __restrict__ XC,
                               const float* __restrict__ UP, const float* __restrict__ onw,
                               const float* __restrict__ skip, float* __restrict__ HF) {
  int r = blockIdx.x, t = threadIdx.x;  // 256 threads; wave == head
  float v = H[(size_t)r * I + t];
  float s1 = v, s2 = v * v;
#pragma unroll
  for (int m = 32; m; m >>= 1) { s1 += __shfl_xor(s1, m); s2 += __shfl_xor(s2, m); }
  float mu = s1 * (1.f / 64), var = s2 * (1.f / 64) - mu * mu;
  float hn = (v - mu) * rsqrtf(var + 1e-5f) * onw[t];
  float zv = UP[(size_t)r * (2 * I) + I + t];
  float hf = (hn + skip[t] * XC[(size_t)r * I + t]) * (zv / (1.f + __expf(-zv)));
  HF[(size_t)r * I + t] = hf;
}

// ---------------- sLSTM gate pre-activations ----------------
__global__ void __launch_bounds__(512) slstm_gates_kernel(const float* __restrict__ xn,
                                                          const float* __restrict__ xc,
                                                          const float* __restrict__ gW,
                                                          const float* __restrict__ bias,
                                                          float* __restrict__ GX) {
  __shared__ float xnl[E], xcl[E];
  int r = blockIdx.x, t = threadIdx.x;  // 512 threads: (n,g,o)
  if (t < E) { xnl[t] = xn[(size_t)r * E + t]; xcl[t] = xc[(size_t)r * E + t]; }
  __syncthreads();
  int n = t >> 7, g = (t >> 5) & 3, o = t & 31;
  const float* src = (g < 2) ? (xcl + n * 32) : (xnl + n * 32);
  const float* wp = gW + (((size_t)g * 4 + n) * 32 + o) * 32;
  float acc = bias[n * 128 + g * 32 + o];
#pragma unroll
  for (int d = 0; d < 32; d++) acc += src[d] * wp[d];
  GX[(size_t)r * 512 + t] = acc;
}

// ---------------- sLSTM scan: one wave per (b,head), h in regs, shuffle matvec ----------------
__global__ void __launch_bounds__(64) slstm_scan2(const float* __restrict__ GX,
                                                  const float* __restrict__ R,
                                                  float* __restrict__ HS) {
  int blk = blockIdx.x;
  int b = blk >> 2, n = blk & 3;
  int l = threadIdx.x;  // 64 lanes; lane handles raw[l] and raw[l+64]
  float R0[32], R1[32];
#pragma unroll
  for (int d = 0; d < 32; d++) {
    R0[d] = R[((size_t)(n * 32 + d)) * 128 + l];
    R1[d] = R[((size_t)(n * 32 + d)) * 128 + 64 + l];
  }
  const float* gxp = GX + ((size_t)b * S) * 512 + n * 128 + l;
  float h_own = 0.f;  // lanes 0..31: h[l]
  float c = 0.f, nn = 0.f, m = 0.f;
  float gx0 = gxp[0], gx1 = gxp[64];
  for (int s = 0; s < S; s++) {
    float r0a = gx0, r0b = 0.f, r1a = gx1, r1b = 0.f;
#pragma unroll
    for (int d = 0; d < 32; d += 2) {
      float hv0 = __shfl(h_own, d);
      float hv1 = __shfl(h_own, d + 1);
      r0a += hv0 * R0[d]; r1a += hv0 * R1[d];
      r0b += hv1 * R0[d + 1]; r1b += hv1 * R1[d + 1];
    }
    float raw0 = r0a + r0b, raw1 = r1a + r1b;
    if (s + 1 < S) { gx0 = gxp[(size_t)(s + 1) * 512]; gx1 = gxp[(size_t)(s + 1) * 512 + 64]; }
    // lanes<32: raw0=i_pre, raw1=z_pre; lanes>=32: raw0=f_pre, raw1=o_pre
    float fr = __shfl_down(raw0, 32);
    float og = __shfl_down(raw1, 32);
    float ir = raw0, zr = raw1;
    float lsf = fminf(fr, 0.f) - __logf(1.f + __expf(-fabsf(fr)));
    float lfm = m + lsf;
    float mn = fmaxf(ir, lfm);
    float iv = __expf(ir - mn), fv = __expf(lfm - mn);
    float th = 1.f - 2.f / (__expf(2.f * zr) + 1.f);  // tanh
    c = fv * c + iv * th;
    nn = fv * nn + iv;
    m = mn;
    float hv = (c / nn) / (1.f + __expf(-og));
    h_own = hv;
    if (l < 32) HS[((size_t)(b * S + s)) * E + n * 32 + l] = hv;
  }
}

// ---------------- sLSTM group-norm (32) + residual add ----------------
__global__ void gnorm_add_kernel(const float* __restrict__ HS, const float* __restrict__ gnw,
                                 float* __restrict__ X) {
  int r = blockIdx.x, t = threadIdx.x;  // 128 threads, groups of 32
  float v = HS[(size_t)r * E + t];
  float s1 = v, s2 = v * v;
#pragma unroll
  for (int m = 16; m; m >>= 1) { s1 += __shfl_xor(s1, m, 32); s2 += __shfl_xor(s2, m, 32); }
  float mu = s1 * (1.f / 32), var = s2 * (1.f / 32) - mu * mu;
  X[(size_t)r * E + t] += (v - mu) * rsqrtf(var + 1e-5f) * gnw[t];
}

// ---------------- GeGLU (exact gelu) ----------------
__global__ void geglu_kernel(const float* __restrict__ U, float* __restrict__ Y) {
  int idx = blockIdx.x * 256 + threadIdx.x;  // BS*192 total
  int r = idx / 192, cc = idx % 192;
  float g = U[(size_t)r * 384 + cc];
  float u = U[(size_t)r * 384 + 192 + cc];
  float ge = 0.5f * g * (1.f + erff(g * 0.70710678118f));
  Y[idx] = ge * u;
}

// ---------------- final LN + FC on last token ----------------
__global__ void head_kernel(const float* __restrict__ X, const float* __restrict__ pw,
                            const float* __restrict__ fcW, const float* __restrict__ fcb,
                            float* __restrict__ out) {
  int b = blockIdx.x, l = threadIdx.x;  // 64
  const float* xr = X + ((size_t)(b * S + S - 1)) * E;
  float2 v = *(const float2*)(xr + l * 2);
  float s1 = v.x + v.y, s2 = v.x * v.x + v.y * v.y;
#pragma unroll
  for (int m = 32; m; m >>= 1) { s1 += __shfl_xor(s1, m); s2 += __shfl_xor(s2, m); }
  float mu = s1 * (1.f / E), var = s2 * (1.f / E) - mu * mu;
  float rr = rsqrtf(var + 1e-5f);
  float2 wv = *(const float2*)(pw + l * 2);
  float2 fw = *(const float2*)(fcW + l * 2);
  float acc = (v.x - mu) * rr * wv.x * fw.x + (v.y - mu) * rr * wv.y * fw.y;
#pragma unroll
  for (int m = 32; m; m >>= 1) acc += __shfl_xor(acc, m);
  if (l == 0) out[b] = acc + fcb[0];
}

extern "C" void kernel_launch(void* const* d_in, const int* in_sizes, int n_in, void* d_out,
                              int out_size, void* d_ws, size_t ws_size, hipStream_t stream) {
  const float* in_x = (const float*)d_in[0];
  const float* m_ln_w = (const float*)d_in[1];
  const float* m_up_W = (const float*)d_in[2];
  const float* m_conv_W = (const float*)d_in[3];
  const float* m_conv_b = (const float*)d_in[4];
  const float* m_q_W = (const float*)d_in[5];
  const float* m_k_W = (const float*)d_in[6];
  const float* m_v_W = (const float*)d_in[7];
  const float* m_ig_W = (const float*)d_in[8];
  const float* m_ig_b = (const float*)d_in[9];
  const float* m_fg_W = (const float*)d_in[10];
  const float* m_fg_b = (const float*)d_in[11];
  const float* m_on_w = (const float*)d_in[12];
  const float* m_skip = (const float*)d_in[13];
  const float* m_down_W = (const float*)d_in[14];
  const float* s_ln_w = (const float*)d_in[15];
  const float* s_conv_W = (const float*)d_in[16];
  const float* s_conv_b = (const float*)d_in[17];
  const float* s_gates_W = (const float*)d_in[18];
  const float* s_R = (const float*)d_in[19];
  const float* s_bias = (const float*)d_in[20];
  const float* s_gn_w = (const float*)d_in[21];
  const float* s_ffn_ln_w = (const float*)d_in[22];
  const float* s_ffn_up_W = (const float*)d_in[23];
  const float* s_ffn_down_W = (const float*)d_in[24];
  const float* post_norm_w = (const float*)d_in[25];
  const float* fc_W = (const float*)d_in[26];
  const float* fc_b = (const float*)d_in[27];

  float* ws = (float*)d_ws;
  float* X = ws;                    // 1,048,576
  float* XN = X + 1048576;          // 1,048,576
  float* UP = XN + 1048576;         // 4,194,304
  float* XC = UP + 4194304;         // 2,097,152
  float* Qb = XC + 2097152;         // 2,097,152
  float* Kb = Qb + 2097152;         // 2,097,152
  float* Vb = Kb + 2097152;         // 2,097,152
  float* Hb = Vb + 2097152;         // 2,097,152
  float* IGb = Hb + 2097152;        // 32,768
  float* FGb = IGb + 32768;
  float* Abuf = FGb + 32768;
  float* Mbuf = Abuf + 32768;
  float* Fbuf = Mbuf + 32768;

  hipMemcpyAsync(X, in_x, (size_t)BS * E * sizeof(float), hipMemcpyDeviceToDevice, stream);

  int mi = 0;
  for (int blk = 0; blk < 7; blk++) {
    if (blk == 1) {
      // ---- sLSTM block ----
      ln_kernel<<<BS, 64, 0, stream>>>(X, s_ln_w, XN);
      conv_silu_kernel<<<BS, E, 0, stream>>>(XN, E, s_conv_W, s_conv_b, XC, E);
      slstm_gates_kernel<<<BS, 512, 0, stream>>>(XN, XC, s_gates_W, s_bias, UP);
      slstm_scan2<<<64, 64, 0, stream>>>(UP, s_R, Hb);
      gnorm_add_kernel<<<BS, E, 0, stream>>>(Hb, s_gn_w, X);
      ln_kernel<<<BS, 64, 0, stream>>>(X, s_ffn_ln_w, XN);
      gemm2<128, 128, false><<<dim3(3, 64), 256, 0, stream>>>(XN, s_ffn_up_W, UP, BS, 384, 128);
      geglu_kernel<<<BS * 192 / 256, 256, 0, stream>>>(UP, XC);
      gemm2<64, 64, true><<<dim3(2, 128), 256, 0, stream>>>(XC, s_ffn_down_W, X, BS, 128, 192);
    } else {
      // ---- mLSTM block (index mi) ----
      const float* ln_w = m_ln_w + (size_t)mi * E;
      const float* up_W = m_up_W + (size_t)mi * E * 512;
      const float* conv_W = m_conv_W + (size_t)mi * I * 4;
      const float* conv_b = m_conv_b + (size_t)mi * I;
      const float* q_W = m_q_W + (size_t)mi * 1024;
      const float* k_W = m_k_W + (size_t)mi * 1024;
      const float* v_W = m_v_W + (size_t)mi * 1024;
      const float* ig_W = m_ig_W + (size_t)mi * 3072;
      const float* ig_b = m_ig_b + (size_t)mi * 4;
      const float* fg_W = m_fg_W + (size_t)mi * 3072;
      const float* fg_b = m_fg_b + (size_t)mi * 4;
      const float* on_w = m_on_w + (size_t)mi * I;
      const float* skipv = m_skip + (size_t)mi * I;
      const float* down_W = m_down_W + (size_t)mi * I * E;

      ln_kernel<<<BS, 64, 0, stream>>>(X, ln_w, XN);
      gemm2<128, 128, false><<<dim3(4, 64), 256, 0, stream>>>(XN, up_W, UP, BS, 512, 128);
      conv_silu_kernel<<<BS, I, 0, stream>>>(UP, 512, conv_W, conv_b, XC, I);
      qkv_kernel<<<BS, I, 0, stream>>>(XC, UP, q_W, k_W, v_W, Qb, Kb, Vb);
      gates_kernel<<<BS, 64, 0, stream>>>(Qb, Kb, Vb, ig_W, ig_b, fg_W, fg_b, IGb, FGb);
      decay_kernel<<<64, 64, 0, stream>>>(IGb, FGb, Abuf, Mbuf, Fbuf);
      attn_kernel<<<512, 256, 0, stream>>>(Qb, Kb, Vb, Abuf, Mbuf, Fbuf, Hb);
      outfuse_kernel<<<BS, I, 0, stream>>>(Hb, XC, UP, on_w, skipv, Qb);  // HF -> Qb
      gemm2<64, 64, true><<<dim3(2, 128), 256, 0, stream>>>(Qb, down_W, X, BS, 128, 256);
      mi++;
    }
  }
  head_kernel<<<B, 64, 0, stream>>>(X, post_norm_w, fc_W, fc_b, (float*)d_out);
}